// Round 2
// baseline (111.413 us; speedup 1.0000x reference)
//
#include <hip/hip_runtime.h>

// PositionalEmbedding: out[b,t,:] = tok_weight[x[b,t],:] + pos_weight[t,:]
// B=4, T=4096, E=512, fp32. Pure memory-bound gather+add.
//
// Structure: one wave (64 lanes) per output row; each lane handles 2 float4
// (cols lane and lane+64) => exactly one 2 KB row per wave, 2 loads + 2
// stores of 16 B/lane, fully coalesced.
//
//  - tok_row is wave-uniform -> readfirstlane puts it in an SGPR, so the
//    gather base is scalar and address math is off the VALU critical path.
//  - Output is write-once/never-read -> nontemporal stores keep the 33.5 MB
//    write stream from evicting tok_w/pos_w (which have reuse: duplicate
//    token ids, pos rows reused 4x across batch) out of the 32 MB L2.
//  - Use native ext_vector_type (not HIP_vector_type float4): the
//    nontemporal builtin only accepts native vector types.

typedef float f32x4 __attribute__((ext_vector_type(4)));

#define TT  4096     // TIME / sequence length
#define EV4 128      // EMBED / 4  (float4 per row)
#define ROWS_PER_BLOCK 4

__global__ __launch_bounds__(256) void pos_embed_kernel(
    const int* __restrict__ x,            // [B*T]
    const f32x4* __restrict__ tok_w,      // [VOCAB, EV4]
    const f32x4* __restrict__ pos_w,      // [TT, EV4]
    f32x4* __restrict__ out,              // [B*T, EV4]
    int nrows)                            // B*T
{
    const int wave = threadIdx.x >> 6;    // 0..3 (one wave per row)
    const int lane = threadIdx.x & 63;
    const int row  = blockIdx.x * ROWS_PER_BLOCK + wave;
    if (row >= nrows) return;             // wave-uniform exit (no divergence)

    const int t = row & (TT - 1);

    // All 64 lanes read the same address; scalarize the result.
    const int tok_row = __builtin_amdgcn_readfirstlane(x[row]);

    const f32x4* __restrict__ ta = tok_w + (size_t)tok_row * EV4;
    const f32x4* __restrict__ pa = pos_w + (size_t)t * EV4;
    f32x4* __restrict__       oa = out   + (size_t)row * EV4;

    // Issue all 4 loads before any use (ILP; compiler schedules vmcnt).
    f32x4 a0 = ta[lane];
    f32x4 a1 = ta[lane + 64];
    f32x4 p0 = pa[lane];
    f32x4 p1 = pa[lane + 64];

    f32x4 r0 = a0 + p0;
    f32x4 r1 = a1 + p1;

    // Write-once stream: don't pollute L2.
    __builtin_nontemporal_store(r0, &oa[lane]);
    __builtin_nontemporal_store(r1, &oa[lane + 64]);
}

extern "C" void kernel_launch(void* const* d_in, const int* in_sizes, int n_in,
                              void* d_out, int out_size, void* d_ws, size_t ws_size,
                              hipStream_t stream) {
    const int*   x     = (const int*)d_in[0];      // [B,T] int32
    const f32x4* tok_w = (const f32x4*)d_in[1];    // [VOCAB, E] fp32
    const f32x4* pos_w = (const f32x4*)d_in[2];    // [T, E] fp32
    f32x4*       out   = (f32x4*)d_out;            // [B,T,E] fp32

    int nrows = out_size / 512;                    // B*T = 16384 rows
    int block = 256;                               // 4 waves = 4 rows/block
    int grid  = (nrows + ROWS_PER_BLOCK - 1) / ROWS_PER_BLOCK;  // 4096

    pos_embed_kernel<<<grid, block, 0, stream>>>(x, tok_w, pos_w, out, nrows);
}